// Round 1
// baseline (1176.351 us; speedup 1.0000x reference)
//
#include <hip/hip_runtime.h>
#include <math.h>

#define Nn 12288
#define Ee 393216
#define INF 256
#define Hh 128
#define DZ 64

// ---------------- degree + norm ----------------
__global__ void deg_kernel(const int* __restrict__ dst, float* __restrict__ deg) {
    int i = blockIdx.x * 256 + threadIdx.x;
    if (i < Ee) atomicAdd(&deg[dst[i]], 1.0f);
}

__global__ void norm_kernel(const float* __restrict__ deg, float* __restrict__ nrm) {
    int i = blockIdx.x * 256 + threadIdx.x;
    if (i < Nn) nrm[i] = 1.0f / sqrtf(fmaxf(deg[i], 1.0f));
}

// ---------------- layer1 GEMM: tmp1 = (X @ W0) * norm  [N,128] ----------------
__global__ __launch_bounds__(128) void gemm1_kernel(const float* __restrict__ X,
                                                    const float* __restrict__ W0,
                                                    const float* __restrict__ nrm,
                                                    float* __restrict__ out) {
    __shared__ float xs[16][INF];  // 16 rows x 256 = 16 KB
    int r0 = blockIdx.x * 16;
    int tid = threadIdx.x;
    const float4* X4 = (const float4*)(X + (size_t)r0 * INF);
    float4* xs4 = (float4*)&xs[0][0];
    for (int idx = tid; idx < 16 * INF / 4; idx += 128) xs4[idx] = X4[idx];
    __syncthreads();
    int j = tid;  // 0..127 output column
    float acc[16];
#pragma unroll
    for (int r = 0; r < 16; ++r) acc[r] = 0.0f;
    for (int k = 0; k < INF; ++k) {
        float w = W0[k * Hh + j];
#pragma unroll
        for (int r = 0; r < 16; ++r) acc[r] += xs[r][k] * w;
    }
#pragma unroll
    for (int r = 0; r < 16; ++r) out[(size_t)(r0 + r) * Hh + j] = acc[r] * nrm[r0 + r];
}

// ---------------- scatter1: agg1[dst] += tmp1[src]  (128 feats/edge) ----------------
__global__ __launch_bounds__(256) void scatter1_kernel(const int* __restrict__ src,
                                                       const int* __restrict__ dst,
                                                       const float* __restrict__ tmp1,
                                                       float* __restrict__ agg1) {
    int e = blockIdx.x * 2 + (threadIdx.x >> 7);
    int f = threadIdx.x & 127;
    int s = src[e], d = dst[e];
    atomicAdd(&agg1[(size_t)d * Hh + f], tmp1[(size_t)s * Hh + f]);
}

// ---------------- layer2 GEMMs (fused m & s): tmp = ((agg1*norm) @ W) * norm ----------------
__global__ __launch_bounds__(128) void gemm2_kernel(const float* __restrict__ agg1,
                                                    const float* __restrict__ Wm,
                                                    const float* __restrict__ Ws,
                                                    const float* __restrict__ nrm_g,
                                                    float* __restrict__ outm,
                                                    float* __restrict__ outs) {
    __shared__ float hs[16][Hh];  // 8 KB
    __shared__ float nl[16];
    int r0 = blockIdx.x * 16;
    int tid = threadIdx.x;
    if (tid < 16) nl[tid] = nrm_g[r0 + tid];
    __syncthreads();
    for (int idx = tid; idx < 16 * Hh / 4; idx += 128) {
        int row = idx >> 5;  // 32 float4 per row
        float4 v = ((const float4*)agg1)[(size_t)r0 * (Hh / 4) + idx];
        float s = nl[row];
        v.x *= s; v.y *= s; v.z *= s; v.w *= s;
        ((float4*)&hs[0][0])[idx] = v;
    }
    __syncthreads();
    int j = tid & 63, sel = tid >> 6;
    const float* W = sel ? Ws : Wm;
    float* out = sel ? outs : outm;
    float acc[16];
#pragma unroll
    for (int r = 0; r < 16; ++r) acc[r] = 0.0f;
    for (int k = 0; k < Hh; ++k) {
        float w = W[k * DZ + j];
#pragma unroll
        for (int r = 0; r < 16; ++r) acc[r] += hs[r][k] * w;
    }
#pragma unroll
    for (int r = 0; r < 16; ++r) out[(size_t)(r0 + r) * DZ + j] = acc[r] * nl[r];
}

// ---------------- scatter2: aggm/aggs[dst] += tmpm/tmps[src] (64 feats/edge) ----------------
__global__ __launch_bounds__(256) void scatter2_kernel(const int* __restrict__ src,
                                                       const int* __restrict__ dst,
                                                       const float* __restrict__ tmpm,
                                                       const float* __restrict__ tmps,
                                                       float* __restrict__ aggm,
                                                       float* __restrict__ aggs) {
    int e = blockIdx.x * 4 + (threadIdx.x >> 6);
    int f = threadIdx.x & 63;
    int s = src[e], d = dst[e];
    atomicAdd(&aggm[(size_t)d * DZ + f], tmpm[(size_t)s * DZ + f]);
    atomicAdd(&aggs[(size_t)d * DZ + f], tmps[(size_t)s * DZ + f]);
}

// ---------------- Z = noise * exp(relu(aggs*norm)) + relu(aggm*norm) ----------------
__global__ void z_kernel(const float* __restrict__ aggm, const float* __restrict__ aggs,
                         const float* __restrict__ noise, const float* __restrict__ nrm,
                         float* __restrict__ Z) {
    int i = blockIdx.x * 256 + threadIdx.x;  // < N*DZ
    int node = i >> 6;
    float nr = nrm[node];
    float m = fmaxf(aggm[i] * nr, 0.0f);
    float s = fmaxf(aggs[i] * nr, 0.0f);
    Z[i] = noise[i] * expf(s) + m;
}

// ---------------- adj = Z @ Z^T  [N,N], fp32, 128x128 tile, 8x8 micro ----------------
// LDS layout swizzle: element (row, c) stored at column ((c & ~3) + 4*(row>>3) + (c&3)) & 63.
// Main-loop reads are then conflict-free (A: 4 distinct banks across ty; B: 2-way across tx).
__global__ __launch_bounds__(256) void zzt_kernel(const float* __restrict__ Z,
                                                  float* __restrict__ out) {
    __shared__ float As[128 * 64];  // 32 KB
    __shared__ float Bs[128 * 64];  // 32 KB
    int i0 = blockIdx.y << 7, j0 = blockIdx.x << 7;
    int tid = threadIdx.x;

    for (int idx = tid; idx < 2048; idx += 256) {
        int row = idx >> 4;
        int c4 = idx & 15;                     // float4 slot in row
        int rot = (row >> 3) << 2;             // rotation, multiple of 4
        int cc = ((c4 << 2) + rot) & 63;       // stays 16B-aligned
        float4 a = *(const float4*)(Z + ((size_t)(i0 + row) << 6) + (c4 << 2));
        float4 b = *(const float4*)(Z + ((size_t)(j0 + row) << 6) + (c4 << 2));
        *(float4*)&As[(row << 6) + cc] = a;
        *(float4*)&Bs[(row << 6) + cc] = b;
    }
    __syncthreads();

    int tx = tid & 15, ty = tid >> 4;
    float acc[8][8];
#pragma unroll
    for (int m = 0; m < 8; ++m)
#pragma unroll
        for (int n = 0; n < 8; ++n) acc[m][n] = 0.0f;

    int arot = ty << 2;  // rows ty*8+m all have (row>>3)==ty
    int brot = tx << 2;
    const float* Abase = &As[(ty << 3) << 6];
    const float* Bbase = &Bs[(tx << 3) << 6];

    for (int k4 = 0; k4 < 16; ++k4) {
        int ka = ((k4 << 2) + arot) & 63;
        int kb = ((k4 << 2) + brot) & 63;
        float4 a4[8], b4[8];
#pragma unroll
        for (int m = 0; m < 8; ++m) a4[m] = *(const float4*)&Abase[(m << 6) + ka];
#pragma unroll
        for (int n = 0; n < 8; ++n) b4[n] = *(const float4*)&Bbase[(n << 6) + kb];
#pragma unroll
        for (int m = 0; m < 8; ++m)
#pragma unroll
            for (int n = 0; n < 8; ++n)
                acc[m][n] += a4[m].x * b4[n].x + a4[m].y * b4[n].y +
                             a4[m].z * b4[n].z + a4[m].w * b4[n].w;
    }

#pragma unroll
    for (int m = 0; m < 8; ++m) {
        size_t row = (size_t)(i0 + (ty << 3) + m);
        float4 v0 = {acc[m][0], acc[m][1], acc[m][2], acc[m][3]};
        float4 v1 = {acc[m][4], acc[m][5], acc[m][6], acc[m][7]};
        *(float4*)(out + row * Nn + j0 + (tx << 3)) = v0;
        *(float4*)(out + row * Nn + j0 + (tx << 3) + 4) = v1;
    }
}

extern "C" void kernel_launch(void* const* d_in, const int* in_sizes, int n_in,
                              void* d_out, int out_size, void* d_ws, size_t ws_size,
                              hipStream_t stream) {
    const float* X = (const float*)d_in[0];
    const float* W0 = (const float*)d_in[1];
    const float* Wm = (const float*)d_in[2];
    const float* Ws = (const float*)d_in[3];
    const float* noise = (const float*)d_in[4];
    const int* ei = (const int*)d_in[5];
    const int* srcp = ei;        // edge_index[0]
    const int* dstp = ei + Ee;   // edge_index[1]
    float* out = (float*)d_out;

    float* ws = (float*)d_ws;
    float* deg  = ws;                    // N
    float* agg1 = deg + Nn;              // N*H
    float* aggm = agg1 + (size_t)Nn * Hh; // N*DZ
    float* aggs = aggm + (size_t)Nn * DZ; // N*DZ
    float* nrm  = aggs + (size_t)Nn * DZ; // N
    float* tmp1 = nrm + Nn;              // N*H
    float* tmpm = tmp1 + (size_t)Nn * Hh; // N*DZ
    float* tmps = tmpm + (size_t)Nn * DZ; // N*DZ
    float* Zb   = tmps + (size_t)Nn * DZ; // N*DZ

    // zero accumulators (deg, agg1, aggm, aggs are contiguous at base)
    size_t zero_bytes = ((size_t)Nn + (size_t)Nn * Hh + 2 * (size_t)Nn * DZ) * sizeof(float);
    hipMemsetAsync(d_ws, 0, zero_bytes, stream);

    deg_kernel<<<(Ee + 255) / 256, 256, 0, stream>>>(dstp, deg);
    norm_kernel<<<(Nn + 255) / 256, 256, 0, stream>>>(deg, nrm);
    gemm1_kernel<<<Nn / 16, 128, 0, stream>>>(X, W0, nrm, tmp1);
    scatter1_kernel<<<Ee / 2, 256, 0, stream>>>(srcp, dstp, tmp1, agg1);
    gemm2_kernel<<<Nn / 16, 128, 0, stream>>>(agg1, Wm, Ws, nrm, tmpm, tmps);
    scatter2_kernel<<<Ee / 4, 256, 0, stream>>>(srcp, dstp, tmpm, tmps, aggm, aggs);
    z_kernel<<<(Nn * DZ) / 256, 256, 0, stream>>>(aggm, aggs, noise, nrm, Zb);
    dim3 g(Nn / 128, Nn / 128);
    zzt_kernel<<<g, 256, 0, stream>>>(Zb, out);
}